// Round 13
// baseline (248.837 us; speedup 1.0000x reference)
//
#include <hip/hip_runtime.h>
#include <math.h>

// DRMM pipeline for MI355X (gfx950) — round 13: L2-blocked gather via
// bucket-sort (token -> (table-range, batch) buckets; ranges fit 4MB L2).
// K1 count -> K2 scan -> K3 scatter -> K4 hist (XCD-swizzled, 8-lane coop,
// bit-identical per-token arithmetic to R12) -> K5 mlp (32-slot partials).
// Fallback to the R12 single-gather path when d_ws < ~17 MB.
// B=32, D=16, L=512, Q=8, E=128, NB=30, NI=100000; RANGE=6250 (16 ranges).

#define BN_INV 0.99950037468777346f  // np.float32(1/sqrt(1+1e-3))

__device__ __forceinline__ float shflx(float v, int m) {
    return __shfl_xor(v, m, 64);
}

__device__ __forceinline__ int sel8i(int v0, int v1, int v2, int v3,
                                     int v4, int v5, int v6, int v7, int i) {
    int a0 = (i & 1) ? v1 : v0;
    int a1 = (i & 1) ? v3 : v2;
    int a2 = (i & 1) ? v5 : v4;
    int a3 = (i & 1) ? v7 : v6;
    int b0 = (i & 2) ? a1 : a0;
    int b1 = (i & 2) ? a3 : a2;
    return (i & 4) ? b1 : b0;
}

__device__ __forceinline__ float sel8f(float v0, float v1, float v2, float v3,
                                       float v4, float v5, float v6, float v7, int i) {
    float a0 = (i & 1) ? v1 : v0;
    float a1 = (i & 1) ? v3 : v2;
    float a2 = (i & 1) ? v5 : v4;
    float a3 = (i & 1) ? v7 : v6;
    float b0 = (i & 2) ? a1 : a0;
    float b1 = (i & 2) ? a3 : a2;
    return (i & 4) ? b1 : b0;
}

// fast tanh: clamp(+-9) then (e^2x-1)/(e^2x+1) via hw exp2 + rcp. (R6-R12: absmax 0.0)
__device__ __forceinline__ float tanh_fast(float x) {
    float y = fminf(fmaxf(x, -9.0f), 9.0f);
    float t = exp2f(y * 2.8853901817f);      // e^(2y)
    return (t - 1.0f) * __builtin_amdgcn_rcpf(t + 1.0f);
}

__device__ __forceinline__ float4 ld4(const float* base, int elem_off) {
    return *(const float4*)(base + elem_off);
}

#define PIN4(V) asm volatile("" : "+v"((V).x), "+v"((V).y), "+v"((V).z), "+v"((V).w))

// FMA body shared by both hist kernels — identical to R9/R11/R12 (absmax 0.0).
#define KSTEP(V, K) {                                                       \
        const int S = (K) * 8 + j;                                          \
        float4 v  = (V);                                                    \
        float4 a0 = qlds[0][S], a1 = qlds[1][S];                            \
        float4 a2 = qlds[2][S], a3 = qlds[3][S];                            \
        float4 a4 = qlds[4][S], a5 = qlds[5][S];                            \
        float4 a6 = qlds[6][S], a7 = qlds[7][S];                            \
        dd = fmaf(v.x, v.x, dd); dd = fmaf(v.y, v.y, dd);                   \
        dd = fmaf(v.z, v.z, dd); dd = fmaf(v.w, v.w, dd);                   \
        dq0 = fmaf(v.x, a0.x, dq0); dq0 = fmaf(v.y, a0.y, dq0);             \
        dq0 = fmaf(v.z, a0.z, dq0); dq0 = fmaf(v.w, a0.w, dq0);             \
        dq1 = fmaf(v.x, a1.x, dq1); dq1 = fmaf(v.y, a1.y, dq1);             \
        dq1 = fmaf(v.z, a1.z, dq1); dq1 = fmaf(v.w, a1.w, dq1);             \
        dq2 = fmaf(v.x, a2.x, dq2); dq2 = fmaf(v.y, a2.y, dq2);             \
        dq2 = fmaf(v.z, a2.z, dq2); dq2 = fmaf(v.w, a2.w, dq2);             \
        dq3 = fmaf(v.x, a3.x, dq3); dq3 = fmaf(v.y, a3.y, dq3);             \
        dq3 = fmaf(v.z, a3.z, dq3); dq3 = fmaf(v.w, a3.w, dq3);             \
        dq4 = fmaf(v.x, a4.x, dq4); dq4 = fmaf(v.y, a4.y, dq4);             \
        dq4 = fmaf(v.z, a4.z, dq4); dq4 = fmaf(v.w, a4.w, dq4);             \
        dq5 = fmaf(v.x, a5.x, dq5); dq5 = fmaf(v.y, a5.y, dq5);             \
        dq5 = fmaf(v.z, a5.z, dq5); dq5 = fmaf(v.w, a5.w, dq5);             \
        dq6 = fmaf(v.x, a6.x, dq6); dq6 = fmaf(v.y, a6.y, dq6);             \
        dq6 = fmaf(v.z, a6.z, dq6); dq6 = fmaf(v.w, a6.w, dq6);             \
        dq7 = fmaf(v.x, a7.x, dq7); dq7 = fmaf(v.y, a7.y, dq7);             \
        dq7 = fmaf(v.z, a7.z, dq7); dq7 = fmaf(v.w, a7.w, dq7);             \
    }

// ---------------- K1: per-bucket token counts ----------------
__global__ __launch_bounds__(512, 4)
void k_count(const int* __restrict__ doc, unsigned* __restrict__ counts)
{
    __shared__ unsigned c[16];
    const int tid = threadIdx.x, bd = blockIdx.x, b = bd >> 4;
    if (tid < 16) c[tid] = 0;
    __syncthreads();
    int idx = doc[bd * 512 + tid];
    atomicAdd(&c[idx / 6250], 1u);
    __syncthreads();
    if (tid < 16) atomicAdd(&counts[tid * 32 + b], c[tid]);   // bucket = r*32+b
}

// ---------------- K2: exclusive scan of 512 counts ----------------
__global__ __launch_bounds__(512, 1)
void k_scan(const unsigned* __restrict__ counts,
            unsigned* __restrict__ offsets, unsigned* __restrict__ cursor)
{
    __shared__ unsigned s[512];
    const int t = threadIdx.x;
    unsigned v = counts[t];
    s[t] = v;
    __syncthreads();
#pragma unroll
    for (int off = 1; off < 512; off <<= 1) {
        unsigned u = (t >= off) ? s[t - off] : 0u;
        __syncthreads();
        s[t] += u;
        __syncthreads();
    }
    unsigned excl = s[t] - v;
    offsets[t] = excl;
    cursor[t]  = excl;
}

// ---------------- K3: scatter packed (bd,idx) by bucket ----------------
__global__ __launch_bounds__(512, 4)
void k_scatter(const int* __restrict__ doc, unsigned* __restrict__ cursor,
               unsigned* __restrict__ packed)
{
    const int tid = threadIdx.x, bd = blockIdx.x, b = bd >> 4;
    int idx = doc[bd * 512 + tid];
    int bucket = (idx / 6250) * 32 + b;
    unsigned pos = atomicAdd(&cursor[bucket], 1u);
    packed[pos] = ((unsigned)bd << 17) | (unsigned)idx;
}

// ---------------- K4: L2-blocked gather + histogram ----------------
__global__ __launch_bounds__(256, 4)
void k_hist_sorted(const unsigned* __restrict__ packed,
                   const unsigned* __restrict__ offsets,
                   const int* __restrict__ query,
                   const float* __restrict__ emb,
                   float* __restrict__ hist_part)   // [32 slot][512 bd][240]
{
    __shared__ float4 qlds[8][32];      // 4KB
    __shared__ float qn_s[8];
    __shared__ float histL[16][8][30];  // 15KB: [d][q][bin]

    const int tid = threadIdx.x;
    const int i   = blockIdx.x;         // 0..1023
    const int xcd   = i & 7;            // heuristic: blockIdx%8 -> XCD
    const int which = i >> 3;           // 0..127
    const int r   = xcd * 2 + (which & 1);      // table range 0..15
    const int b   = (which >> 1) & 31;           // batch
    const int sub = which >> 6;                   // 0..1
    const int bucket = r * 32 + b;

    const unsigned beg = offsets[bucket];
    const unsigned end = (bucket == 511) ? 262144u : offsets[bucket + 1];
    const unsigned len = end - beg;
    const unsigned s0 = beg + (len * (unsigned)sub) / 2u;
    const unsigned s1 = beg + (len * (unsigned)(sub + 1)) / 2u;

    for (int t = tid; t < 16 * 8 * 30; t += 256) ((float*)histL)[t] = 0.0f;

    // wave-uniform (b is block-uniform) query indices + LDS staging
    const int* qrow = query + b * 8;
    const int qi0 = __builtin_amdgcn_readfirstlane(qrow[0]);
    const int qi1 = __builtin_amdgcn_readfirstlane(qrow[1]);
    const int qi2 = __builtin_amdgcn_readfirstlane(qrow[2]);
    const int qi3 = __builtin_amdgcn_readfirstlane(qrow[3]);
    const int qi4 = __builtin_amdgcn_readfirstlane(qrow[4]);
    const int qi5 = __builtin_amdgcn_readfirstlane(qrow[5]);
    const int qi6 = __builtin_amdgcn_readfirstlane(qrow[6]);
    const int qi7 = __builtin_amdgcn_readfirstlane(qrow[7]);
    {
        int q = tid >> 5, c = tid & 31;
        int qis = sel8i(qi0, qi1, qi2, qi3, qi4, qi5, qi6, qi7, q);
        qlds[q][c] = *((const float4*)(emb + (size_t)qis * 128) + c);
    }
    __syncthreads();

    // query norms (wave 0) — values & op order identical to R11/R12 (absmax 0.0)
    if ((tid >> 6) == 0) {
        int lane = tid & 63;
        int q = lane >> 3, jj = lane & 7;
        float s = 0.f;
#pragma unroll
        for (int c = 0; c < 4; ++c) {
            float4 x = qlds[q][jj * 4 + c];
            s = fmaf(x.x, x.x, s); s = fmaf(x.y, x.y, s);
            s = fmaf(x.z, x.z, s); s = fmaf(x.w, x.w, s);
        }
        s += shflx(s, 1); s += shflx(s, 2); s += shflx(s, 4);
        if (jj == 0) qn_s[q] = sqrtf(s);
    }
    __syncthreads();

    const int g32 = tid >> 3;   // group 0..31
    const int j   = tid & 7;    // lane in group
    const unsigned nit = (s1 - s0 + 31u) >> 5;

    for (unsigned it = 0; it < nit; ++it) {
        unsigned t = s0 + it * 32u + (unsigned)g32;
        const bool act = t < s1;
        unsigned tr = act ? t : (s1 > 0 ? s1 - 1u : 0u);
        unsigned p  = packed[tr];
        int idx = (int)(p & 0x1FFFFu);
        int d   = (int)((p >> 17) & 15u);

        const float* rbase = emb + (size_t)idx * 128;
        const int eo = j * 4;
        float4 A0 = ld4(rbase, eo);
        float4 A1 = ld4(rbase, eo + 32);
        float4 A2 = ld4(rbase, eo + 64);
        float4 A3 = ld4(rbase, eo + 96);

        float dd = 0.f;
        float dq0 = 0.f, dq1 = 0.f, dq2 = 0.f, dq3 = 0.f;
        float dq4 = 0.f, dq5 = 0.f, dq6 = 0.f, dq7 = 0.f;

        PIN4(A0); KSTEP(A0, 0)
        PIN4(A1); KSTEP(A1, 1)
        PIN4(A2); KSTEP(A2, 2)
        PIN4(A3); KSTEP(A3, 3)

#pragma unroll
        for (int off = 1; off <= 4; off <<= 1) {
            dd  += shflx(dd, off);
            dq0 += shflx(dq0, off); dq1 += shflx(dq1, off);
            dq2 += shflx(dq2, off); dq3 += shflx(dq3, off);
            dq4 += shflx(dq4, off); dq5 += shflx(dq5, off);
            dq6 += shflx(dq6, off); dq7 += shflx(dq7, off);
        }

        if (act) {
            float dqj = sel8f(dq0, dq1, dq2, dq3, dq4, dq5, dq6, dq7, j);
            float sim = dqj / (sqrtf(dd) * qn_s[j] + 1e-8f);
            float u = (sim - 0.001f) / 0.999f * 30.0f;   // ref op order
            int bin = (int)floorf(u);
            bin = bin < 0 ? 0 : (bin > 29 ? 29 : bin);
            atomicAdd(&histL[d][j][bin], 1.0f);
        }
    }
    __syncthreads();

    // flush: slot-private slice, plain stores (exact integer counts)
    const int slot = r * 2 + sub;                 // 0..31
    float* dst = hist_part + (size_t)slot * 512 * 240 + (size_t)b * 3840;
    for (int t = tid; t < 3840; t += 256) dst[t] = ((float*)histL)[t];
}

// ---------------- R12 fallback: single-pass gather + histogram --------------
__global__ __launch_bounds__(512, 8)
void drmm_hist_atomic(const int* __restrict__ doc,
                      const int* __restrict__ query,
                      const float* __restrict__ emb,
                      float* __restrict__ hist_out)   // [512][240], pre-zeroed
{
    __shared__ float histw[8][8][32];
    __shared__ float qn_s[8];
    __shared__ float4 qlds[8][32];

    const int tid  = threadIdx.x;
    const int bid  = blockIdx.x;
    const int b    = bid >> 7;
    const int wid  = tid >> 6;
    const int lane = tid & 63;
    const int j    = tid & 7;

    const int gtok = bid * 64 + (tid >> 3);
    const int idx  = doc[gtok];

    for (int t = tid; t < 8 * 8 * 32; t += 512) ((float*)histw)[t] = 0.0f;

    const int* qrow = query + b * 8;
    const int qi0 = __builtin_amdgcn_readfirstlane(qrow[0]);
    const int qi1 = __builtin_amdgcn_readfirstlane(qrow[1]);
    const int qi2 = __builtin_amdgcn_readfirstlane(qrow[2]);
    const int qi3 = __builtin_amdgcn_readfirstlane(qrow[3]);
    const int qi4 = __builtin_amdgcn_readfirstlane(qrow[4]);
    const int qi5 = __builtin_amdgcn_readfirstlane(qrow[5]);
    const int qi6 = __builtin_amdgcn_readfirstlane(qrow[6]);
    const int qi7 = __builtin_amdgcn_readfirstlane(qrow[7]);
    if (tid < 256) {
        int q = tid >> 5, c = tid & 31;
        int qis = sel8i(qi0, qi1, qi2, qi3, qi4, qi5, qi6, qi7, q);
        qlds[q][c] = *((const float4*)(emb + (size_t)qis * 128) + c);
    }
    __syncthreads();

    if (wid == 0) {
        int q = lane >> 3, jj = lane & 7;
        float s = 0.f;
#pragma unroll
        for (int c = 0; c < 4; ++c) {
            float4 x = qlds[q][jj * 4 + c];
            s = fmaf(x.x, x.x, s); s = fmaf(x.y, x.y, s);
            s = fmaf(x.z, x.z, s); s = fmaf(x.w, x.w, s);
        }
        s += shflx(s, 1); s += shflx(s, 2); s += shflx(s, 4);
        if (jj == 0) qn_s[q] = sqrtf(s);
    }

    const float* rbase = emb + (size_t)idx * 128;
    const int eo = j * 4;
    float4 A0 = ld4(rbase, eo);
    float4 A1 = ld4(rbase, eo + 32);
    float4 A2 = ld4(rbase, eo + 64);
    float4 A3 = ld4(rbase, eo + 96);

    float dd = 0.f;
    float dq0 = 0.f, dq1 = 0.f, dq2 = 0.f, dq3 = 0.f;
    float dq4 = 0.f, dq5 = 0.f, dq6 = 0.f, dq7 = 0.f;

    PIN4(A0); KSTEP(A0, 0)
    PIN4(A1); KSTEP(A1, 1)
    PIN4(A2); KSTEP(A2, 2)
    PIN4(A3); KSTEP(A3, 3)

#pragma unroll
    for (int off = 1; off <= 4; off <<= 1) {
        dd  += shflx(dd, off);
        dq0 += shflx(dq0, off); dq1 += shflx(dq1, off);
        dq2 += shflx(dq2, off); dq3 += shflx(dq3, off);
        dq4 += shflx(dq4, off); dq5 += shflx(dq5, off);
        dq6 += shflx(dq6, off); dq7 += shflx(dq7, off);
    }
    __syncthreads();

    {
        float dqj = sel8f(dq0, dq1, dq2, dq3, dq4, dq5, dq6, dq7, j);
        float sim = dqj / (sqrtf(dd) * qn_s[j] + 1e-8f);
        float u = (sim - 0.001f) / 0.999f * 30.0f;
        int bin = (int)floorf(u);
        bin = bin < 0 ? 0 : (bin > 29 ? 29 : bin);
        atomicAdd(&histw[wid][j][bin], 1.0f);
    }
    __syncthreads();

    if (tid < 240) {
        int q = tid / 30, k = tid - q * 30;
        float s = ((histw[0][q][k] + histw[1][q][k])
                 + (histw[2][q][k] + histw[3][q][k]))
                + ((histw[4][q][k] + histw[5][q][k])
                 + (histw[6][q][k] + histw[7][q][k]));
        atomicAdd(&hist_out[(bid >> 3) * 240 + tid], s);
    }
}

// ---------------- K5: gate softmax + MLP + output ----------------
// MODE 0: hist_g is [512][240] final counts. MODE 2: 32-slot partials.
template <int MODE>
__global__ __launch_bounds__(512, 3)
void drmm_mlp(const float* __restrict__ hist_g,
              const int* __restrict__ query,
              const float* __restrict__ idf,
              const float* __restrict__ w_gate,
              const float* __restrict__ g_in, const float* __restrict__ b_in,
              const float* __restrict__ W0, const float* __restrict__ b0,
              const float* __restrict__ g0, const float* __restrict__ be0,
              const float* __restrict__ W1, const float* __restrict__ b1,
              const float* __restrict__ g1, const float* __restrict__ be1,
              const float* __restrict__ W2, const float* __restrict__ b2,
              const float* __restrict__ g2, const float* __restrict__ be2,
              const float* __restrict__ W3, const float* __restrict__ b3,
              const float* __restrict__ g3, const float* __restrict__ be3,
              float* __restrict__ out)
{
    __shared__ float W1l[8192];
    __shared__ float xrow[8][30];
    __shared__ float h1s[8][128];
    __shared__ float h2s[8][64];
    __shared__ float h3s[8][32];
    __shared__ float gate_s[8];
    __shared__ float part[8];

    const int tid  = threadIdx.x;
    const int bd   = blockIdx.x;
    const int b    = bd >> 4;
    const int wid  = tid >> 6;
    const int lane = tid & 63;

#pragma unroll
    for (int i = 0; i < 4; ++i)
        ((float4*)W1l)[tid + i * 512] = ((const float4*)W1)[tid + i * 512];

    if (tid >= 504) {
        int q = tid - 504;
        float z = w_gate[q] * idf[query[b * 8 + q]];
        float m = z;
        m = fmaxf(m, shflx(m, 1)); m = fmaxf(m, shflx(m, 2)); m = fmaxf(m, shflx(m, 4));
        float e = expf(z - m);
        float s = e;
        s += shflx(s, 1); s += shflx(s, 2); s += shflx(s, 4);
        gate_s[q] = e / s;
    }

    if (tid < 240) {
        int q = tid / 30, k = tid - q * 30;
        float s;
        if (MODE == 2) {
            const float* hp = hist_g + (size_t)bd * 240 + tid;
            s = 0.f;
#pragma unroll
            for (int slot = 0; slot < 32; ++slot)
                s += hp[(size_t)slot * 512 * 240];   // exact int counts
        } else {
            s = hist_g[bd * 240 + tid];
        }
        xrow[q][k] = g_in[k] * (s * BN_INV) + b_in[k];
    }
    __syncthreads();

    {
        float a0 = 0.f, a1 = 0.f;
#pragma unroll
        for (int k = 0; k < 30; ++k) {
            float xk = xrow[wid][k];
            a0 += xk * W0[k * 128 + lane];
            a1 += xk * W0[k * 128 + 64 + lane];
        }
        a0 += b0[lane]; a1 += b0[lane + 64];
        h1s[wid][lane]      = tanh_fast(g0[lane]      * (a0 * BN_INV) + be0[lane]);
        h1s[wid][lane + 64] = tanh_fast(g0[lane + 64] * (a1 * BN_INV) + be0[lane + 64]);
    }
    __syncthreads();

    {
        float a = 0.f;
#pragma unroll 16
        for (int k = 0; k < 128; ++k) a += h1s[wid][k] * W1l[k * 64 + lane];
        a += b1[lane];
        h2s[wid][lane] = tanh_fast(g1[lane] * (a * BN_INV) + be1[lane]);
    }
    __syncthreads();

    if (lane < 32) {
        float a = 0.f;
#pragma unroll 8
        for (int k = 0; k < 64; ++k) a += h2s[wid][k] * W2[k * 32 + lane];
        a += b2[lane];
        h3s[wid][lane] = tanh_fast(g2[lane] * (a * BN_INV) + be2[lane]);
    }

    if (lane == 0) {
        float a = 0.f;
#pragma unroll
        for (int k = 0; k < 32; ++k) a += h3s[wid][k] * W3[k];
        a += b3[0];
        float y = tanh_fast(g3[0] * (a * BN_INV) + be3[0]);
        part[wid] = gate_s[wid] * y;
    }
    __syncthreads();

    if (tid == 0) {
        float s = 0.f;
#pragma unroll
        for (int q = 0; q < 8; ++q) s += part[q];
        out[bd] = s;
    }
}

extern "C" void kernel_launch(void* const* d_in, const int* in_sizes, int n_in,
                              void* d_out, int out_size, void* d_ws, size_t ws_size,
                              hipStream_t stream) {
    (void)in_sizes; (void)n_in; (void)out_size;
    const int*   doc    = (const int*)d_in[0];
    const int*   query  = (const int*)d_in[1];
    const float* emb    = (const float*)d_in[2];
    const float* idf    = (const float*)d_in[3];
    const float* w_gate = (const float*)d_in[4];
    const float* g_in   = (const float*)d_in[5];
    const float* b_in   = (const float*)d_in[6];
    const float* W0  = (const float*)d_in[7];
    const float* b0  = (const float*)d_in[8];
    const float* g0  = (const float*)d_in[9];
    const float* be0 = (const float*)d_in[10];
    const float* W1  = (const float*)d_in[11];
    const float* b1  = (const float*)d_in[12];
    const float* g1  = (const float*)d_in[13];
    const float* be1 = (const float*)d_in[14];
    const float* W2  = (const float*)d_in[15];
    const float* b2  = (const float*)d_in[16];
    const float* g2  = (const float*)d_in[17];
    const float* be2 = (const float*)d_in[18];
    const float* W3  = (const float*)d_in[19];
    const float* b3  = (const float*)d_in[20];
    const float* g3  = (const float*)d_in[21];
    const float* be3 = (const float*)d_in[22];

    const size_t HIST_PART_B = (size_t)32 * 512 * 240 * sizeof(float); // 15,728,640
    const size_t need_sorted = HIST_PART_B + 3 * 512 * sizeof(unsigned)
                             + (size_t)262144 * sizeof(unsigned);      // ~16.8 MB

    if (ws_size >= need_sorted) {
        float*    hist_part = (float*)d_ws;
        unsigned* counts  = (unsigned*)((char*)d_ws + HIST_PART_B);
        unsigned* offsets = counts + 512;
        unsigned* cursor  = offsets + 512;
        unsigned* packed  = cursor + 512;

        hipMemsetAsync(counts, 0, 512 * sizeof(unsigned), stream);
        k_count  <<<dim3(512),  dim3(512), 0, stream>>>(doc, counts);
        k_scan   <<<dim3(1),    dim3(512), 0, stream>>>(counts, offsets, cursor);
        k_scatter<<<dim3(512),  dim3(512), 0, stream>>>(doc, cursor, packed);
        k_hist_sorted<<<dim3(1024), dim3(256), 0, stream>>>(
            packed, offsets, query, emb, hist_part);
        drmm_mlp<2><<<dim3(512), dim3(512), 0, stream>>>(
            hist_part, query, idf, w_gate, g_in, b_in,
            W0, b0, g0, be0, W1, b1, g1, be1,
            W2, b2, g2, be2, W3, b3, g3, be3, (float*)d_out);
    } else {
        float* hist_g = (float*)d_ws;
        hipMemsetAsync(hist_g, 0, 512 * 240 * sizeof(float), stream);
        drmm_hist_atomic<<<dim3(4096), dim3(512), 0, stream>>>(doc, query, emb, hist_g);
        drmm_mlp<0><<<dim3(512), dim3(512), 0, stream>>>(
            hist_g, query, idf, w_gate, g_in, b_in,
            W0, b0, g0, be0, W1, b1, g1, be1,
            W2, b2, g2, be2, W3, b3, g3, be3, (float*)d_out);
    }
}

// Round 14
// 63.175 us; speedup vs baseline: 3.9388x; 3.9388x over previous
//
#include <hip/hip_runtime.h>
#include <math.h>

// DRMM pipeline for MI355X (gfx950) — round 14: L2-blocked gather, take 2.
// Sort is now contention-free: K1 count (plain stores, [16][32][16]) ->
// K2 one-block exclusive scan (8192 entries) -> K3 scatter (LDS-local
// cursors, deterministic bases, NO global atomics) -> K4 hist (one bucket
// per block, XCD-phased ranges, bit-identical token math to R12) -> K5 mlp.
// Fallback to the R12 single-pass path when d_ws < ~9.1 MB.
// B=32, D=16, L=512, Q=8, E=128, NB=30, NI=100000; 16 ranges of 6250 rows.

#define BN_INV 0.99950037468777346f  // np.float32(1/sqrt(1+1e-3))

__device__ __forceinline__ float shflx(float v, int m) {
    return __shfl_xor(v, m, 64);
}

__device__ __forceinline__ int sel8i(int v0, int v1, int v2, int v3,
                                     int v4, int v5, int v6, int v7, int i) {
    int a0 = (i & 1) ? v1 : v0;
    int a1 = (i & 1) ? v3 : v2;
    int a2 = (i & 1) ? v5 : v4;
    int a3 = (i & 1) ? v7 : v6;
    int b0 = (i & 2) ? a1 : a0;
    int b1 = (i & 2) ? a3 : a2;
    return (i & 4) ? b1 : b0;
}

__device__ __forceinline__ float sel8f(float v0, float v1, float v2, float v3,
                                       float v4, float v5, float v6, float v7, int i) {
    float a0 = (i & 1) ? v1 : v0;
    float a1 = (i & 1) ? v3 : v2;
    float a2 = (i & 1) ? v5 : v4;
    float a3 = (i & 1) ? v7 : v6;
    float b0 = (i & 2) ? a1 : a0;
    float b1 = (i & 2) ? a3 : a2;
    return (i & 4) ? b1 : b0;
}

// fast tanh: clamp(+-9) then (e^2x-1)/(e^2x+1) via hw exp2 + rcp. (R6-R13: absmax 0.0)
__device__ __forceinline__ float tanh_fast(float x) {
    float y = fminf(fmaxf(x, -9.0f), 9.0f);
    float t = exp2f(y * 2.8853901817f);      // e^(2y)
    return (t - 1.0f) * __builtin_amdgcn_rcpf(t + 1.0f);
}

__device__ __forceinline__ float4 ld4(const float* base, int elem_off) {
    return *(const float4*)(base + elem_off);
}

#define PIN4(V) asm volatile("" : "+v"((V).x), "+v"((V).y), "+v"((V).z), "+v"((V).w))

// FMA body — identical to R9/R11/R12 (absmax 0.0).
#define KSTEP(V, K) {                                                       \
        const int S = (K) * 8 + j;                                          \
        float4 v  = (V);                                                    \
        float4 a0 = qlds[0][S], a1 = qlds[1][S];                            \
        float4 a2 = qlds[2][S], a3 = qlds[3][S];                            \
        float4 a4 = qlds[4][S], a5 = qlds[5][S];                            \
        float4 a6 = qlds[6][S], a7 = qlds[7][S];                            \
        dd = fmaf(v.x, v.x, dd); dd = fmaf(v.y, v.y, dd);                   \
        dd = fmaf(v.z, v.z, dd); dd = fmaf(v.w, v.w, dd);                   \
        dq0 = fmaf(v.x, a0.x, dq0); dq0 = fmaf(v.y, a0.y, dq0);             \
        dq0 = fmaf(v.z, a0.z, dq0); dq0 = fmaf(v.w, a0.w, dq0);             \
        dq1 = fmaf(v.x, a1.x, dq1); dq1 = fmaf(v.y, a1.y, dq1);             \
        dq1 = fmaf(v.z, a1.z, dq1); dq1 = fmaf(v.w, a1.w, dq1);             \
        dq2 = fmaf(v.x, a2.x, dq2); dq2 = fmaf(v.y, a2.y, dq2);             \
        dq2 = fmaf(v.z, a2.z, dq2); dq2 = fmaf(v.w, a2.w, dq2);             \
        dq3 = fmaf(v.x, a3.x, dq3); dq3 = fmaf(v.y, a3.y, dq3);             \
        dq3 = fmaf(v.z, a3.z, dq3); dq3 = fmaf(v.w, a3.w, dq3);             \
        dq4 = fmaf(v.x, a4.x, dq4); dq4 = fmaf(v.y, a4.y, dq4);             \
        dq4 = fmaf(v.z, a4.z, dq4); dq4 = fmaf(v.w, a4.w, dq4);             \
        dq5 = fmaf(v.x, a5.x, dq5); dq5 = fmaf(v.y, a5.y, dq5);             \
        dq5 = fmaf(v.z, a5.z, dq5); dq5 = fmaf(v.w, a5.w, dq5);             \
        dq6 = fmaf(v.x, a6.x, dq6); dq6 = fmaf(v.y, a6.y, dq6);             \
        dq6 = fmaf(v.z, a6.z, dq6); dq6 = fmaf(v.w, a6.w, dq6);             \
        dq7 = fmaf(v.x, a7.x, dq7); dq7 = fmaf(v.y, a7.y, dq7);             \
        dq7 = fmaf(v.z, a7.z, dq7); dq7 = fmaf(v.w, a7.w, dq7);             \
    }

// ---------------- K1: per-(range, source-block) counts — plain stores -------
__global__ __launch_bounds__(512, 4)
void k_count(const int* __restrict__ doc, unsigned* __restrict__ counts)
{
    __shared__ unsigned c[16];
    const int tid = threadIdx.x, bd = blockIdx.x;
    const int b = bd >> 4, sb = bd & 15;
    if (tid < 16) c[tid] = 0;
    __syncthreads();
    int idx = doc[bd * 512 + tid];
    atomicAdd(&c[idx / 6250], 1u);
    __syncthreads();
    // counts layout: [(r*32 + b)*16 + sb] — unique slot per (r, source block)
    if (tid < 16) counts[(tid * 32 + b) * 16 + sb] = c[tid];
}

// ---------------- K2: one-block exclusive scan of 8192 counts ----------------
__global__ __launch_bounds__(512, 1)
void k_scan(const unsigned* __restrict__ counts, unsigned* __restrict__ offsets)
{
    __shared__ unsigned s[512];
    const int t = threadIdx.x;
    unsigned loc[16];
    unsigned sum = 0;
#pragma unroll
    for (int i = 0; i < 16; ++i) { loc[i] = counts[t * 16 + i]; sum += loc[i]; }
    s[t] = sum;
    __syncthreads();
#pragma unroll
    for (int off = 1; off < 512; off <<= 1) {
        unsigned u = (t >= off) ? s[t - off] : 0u;
        __syncthreads();
        s[t] += u;
        __syncthreads();
    }
    unsigned excl = s[t] - sum;
#pragma unroll
    for (int i = 0; i < 16; ++i) { offsets[t * 16 + i] = excl; excl += loc[i]; }
}

// ---------------- K3: scatter with deterministic bases (no global atomics) --
__global__ __launch_bounds__(512, 4)
void k_scatter(const int* __restrict__ doc, const unsigned* __restrict__ offsets,
               unsigned* __restrict__ packed)
{
    __shared__ unsigned cur[16];
    const int tid = threadIdx.x, bd = blockIdx.x;
    const int b = bd >> 4, sb = bd & 15;
    if (tid < 16) cur[tid] = offsets[(tid * 32 + b) * 16 + sb];
    __syncthreads();
    int idx = doc[bd * 512 + tid];
    unsigned pos = atomicAdd(&cur[idx / 6250], 1u);   // LDS atomic only
    packed[pos] = ((unsigned)bd << 17) | (unsigned)idx;
}

// ---------------- K4: L2-blocked gather + histogram (1 bucket / block) ------
__global__ __launch_bounds__(512, 2)
void k_hist_sorted(const unsigned* __restrict__ packed,
                   const unsigned* __restrict__ offsets,
                   const int* __restrict__ query,
                   const float* __restrict__ emb,
                   float* __restrict__ hist_part)   // [16 slot][512 bd][240]
{
    __shared__ float4 qlds[8][32];      // 4KB
    __shared__ float qn_s[8];
    __shared__ float histL[16][8][30];  // 15KB: [d][q][bin]

    const int tid = threadIdx.x;
    const int i   = blockIdx.x;         // 0..511
    const int xcd   = i & 7;            // heuristic: blockIdx%8 -> XCD
    const int which = i >> 3;           // 0..63
    const int r   = xcd * 2 + (which >> 5);      // XCD phase A then B
    const int b   = which & 31;
    const int bucket = r * 32 + b;

    const unsigned beg = offsets[(size_t)bucket * 16];
    const unsigned end = (bucket == 511) ? 262144u
                       : offsets[(size_t)(bucket + 1) * 16];

    for (int t = tid; t < 16 * 8 * 30; t += 512) ((float*)histL)[t] = 0.0f;

    const int* qrow = query + b * 8;
    const int qi0 = __builtin_amdgcn_readfirstlane(qrow[0]);
    const int qi1 = __builtin_amdgcn_readfirstlane(qrow[1]);
    const int qi2 = __builtin_amdgcn_readfirstlane(qrow[2]);
    const int qi3 = __builtin_amdgcn_readfirstlane(qrow[3]);
    const int qi4 = __builtin_amdgcn_readfirstlane(qrow[4]);
    const int qi5 = __builtin_amdgcn_readfirstlane(qrow[5]);
    const int qi6 = __builtin_amdgcn_readfirstlane(qrow[6]);
    const int qi7 = __builtin_amdgcn_readfirstlane(qrow[7]);
    if (tid < 256) {
        int q = tid >> 5, c = tid & 31;
        int qis = sel8i(qi0, qi1, qi2, qi3, qi4, qi5, qi6, qi7, q);
        qlds[q][c] = *((const float4*)(emb + (size_t)qis * 128) + c);
    }
    __syncthreads();

    // query norms (wave 0) — values & op order identical to R11/R12 (absmax 0.0)
    if ((tid >> 6) == 0) {
        int lane = tid & 63;
        int q = lane >> 3, jj = lane & 7;
        float s = 0.f;
#pragma unroll
        for (int c = 0; c < 4; ++c) {
            float4 x = qlds[q][jj * 4 + c];
            s = fmaf(x.x, x.x, s); s = fmaf(x.y, x.y, s);
            s = fmaf(x.z, x.z, s); s = fmaf(x.w, x.w, s);
        }
        s += shflx(s, 1); s += shflx(s, 2); s += shflx(s, 4);
        if (jj == 0) qn_s[q] = sqrtf(s);
    }
    __syncthreads();

    const int g64 = tid >> 3;   // group 0..63
    const int j   = tid & 7;
    const unsigned len = end - beg;
    const unsigned nit = (len + 63u) >> 6;

    for (unsigned it = 0; it < nit; ++it) {
        unsigned t = beg + it * 64u + (unsigned)g64;
        const bool act = t < end;
        unsigned tr = act ? t : (end - 1u);
        unsigned p  = packed[tr];
        int idx = (int)(p & 0x1FFFFu);
        int d   = (int)((p >> 17) & 15u);

        const float* rbase = emb + (size_t)idx * 128;
        const int eo = j * 4;
        float4 A0 = ld4(rbase, eo);
        float4 A1 = ld4(rbase, eo + 32);
        float4 A2 = ld4(rbase, eo + 64);
        float4 A3 = ld4(rbase, eo + 96);

        float dd = 0.f;
        float dq0 = 0.f, dq1 = 0.f, dq2 = 0.f, dq3 = 0.f;
        float dq4 = 0.f, dq5 = 0.f, dq6 = 0.f, dq7 = 0.f;

        PIN4(A0); KSTEP(A0, 0)
        PIN4(A1); KSTEP(A1, 1)
        PIN4(A2); KSTEP(A2, 2)
        PIN4(A3); KSTEP(A3, 3)

#pragma unroll
        for (int off = 1; off <= 4; off <<= 1) {
            dd  += shflx(dd, off);
            dq0 += shflx(dq0, off); dq1 += shflx(dq1, off);
            dq2 += shflx(dq2, off); dq3 += shflx(dq3, off);
            dq4 += shflx(dq4, off); dq5 += shflx(dq5, off);
            dq6 += shflx(dq6, off); dq7 += shflx(dq7, off);
        }

        if (act) {
            float dqj = sel8f(dq0, dq1, dq2, dq3, dq4, dq5, dq6, dq7, j);
            float sim = dqj / (sqrtf(dd) * qn_s[j] + 1e-8f);
            float u = (sim - 0.001f) / 0.999f * 30.0f;   // ref op order
            int bin = (int)floorf(u);
            bin = bin < 0 ? 0 : (bin > 29 ? 29 : bin);
            atomicAdd(&histL[d][j][bin], 1.0f);
        }
    }
    __syncthreads();

    // flush: slot r, bds b*16..b*16+15 — disjoint slices, plain stores
    float* dst = hist_part + (size_t)r * 512 * 240 + (size_t)b * 16 * 240;
    for (int t = tid; t < 3840; t += 512) dst[t] = ((float*)histL)[t];
}

// ---------------- R12 fallback: single-pass gather + histogram --------------
__global__ __launch_bounds__(512, 8)
void drmm_hist_atomic(const int* __restrict__ doc,
                      const int* __restrict__ query,
                      const float* __restrict__ emb,
                      float* __restrict__ hist_out)   // [512][240], pre-zeroed
{
    __shared__ float histw[8][8][32];
    __shared__ float qn_s[8];
    __shared__ float4 qlds[8][32];

    const int tid  = threadIdx.x;
    const int bid  = blockIdx.x;
    const int b    = bid >> 7;
    const int wid  = tid >> 6;
    const int lane = tid & 63;
    const int j    = tid & 7;

    const int gtok = bid * 64 + (tid >> 3);
    const int idx  = doc[gtok];

    for (int t = tid; t < 8 * 8 * 32; t += 512) ((float*)histw)[t] = 0.0f;

    const int* qrow = query + b * 8;
    const int qi0 = __builtin_amdgcn_readfirstlane(qrow[0]);
    const int qi1 = __builtin_amdgcn_readfirstlane(qrow[1]);
    const int qi2 = __builtin_amdgcn_readfirstlane(qrow[2]);
    const int qi3 = __builtin_amdgcn_readfirstlane(qrow[3]);
    const int qi4 = __builtin_amdgcn_readfirstlane(qrow[4]);
    const int qi5 = __builtin_amdgcn_readfirstlane(qrow[5]);
    const int qi6 = __builtin_amdgcn_readfirstlane(qrow[6]);
    const int qi7 = __builtin_amdgcn_readfirstlane(qrow[7]);
    if (tid < 256) {
        int q = tid >> 5, c = tid & 31;
        int qis = sel8i(qi0, qi1, qi2, qi3, qi4, qi5, qi6, qi7, q);
        qlds[q][c] = *((const float4*)(emb + (size_t)qis * 128) + c);
    }
    __syncthreads();

    if (wid == 0) {
        int q = lane >> 3, jj = lane & 7;
        float s = 0.f;
#pragma unroll
        for (int c = 0; c < 4; ++c) {
            float4 x = qlds[q][jj * 4 + c];
            s = fmaf(x.x, x.x, s); s = fmaf(x.y, x.y, s);
            s = fmaf(x.z, x.z, s); s = fmaf(x.w, x.w, s);
        }
        s += shflx(s, 1); s += shflx(s, 2); s += shflx(s, 4);
        if (jj == 0) qn_s[q] = sqrtf(s);
    }

    const float* rbase = emb + (size_t)idx * 128;
    const int eo = j * 4;
    float4 A0 = ld4(rbase, eo);
    float4 A1 = ld4(rbase, eo + 32);
    float4 A2 = ld4(rbase, eo + 64);
    float4 A3 = ld4(rbase, eo + 96);

    float dd = 0.f;
    float dq0 = 0.f, dq1 = 0.f, dq2 = 0.f, dq3 = 0.f;
    float dq4 = 0.f, dq5 = 0.f, dq6 = 0.f, dq7 = 0.f;

    PIN4(A0); KSTEP(A0, 0)
    PIN4(A1); KSTEP(A1, 1)
    PIN4(A2); KSTEP(A2, 2)
    PIN4(A3); KSTEP(A3, 3)

#pragma unroll
    for (int off = 1; off <= 4; off <<= 1) {
        dd  += shflx(dd, off);
        dq0 += shflx(dq0, off); dq1 += shflx(dq1, off);
        dq2 += shflx(dq2, off); dq3 += shflx(dq3, off);
        dq4 += shflx(dq4, off); dq5 += shflx(dq5, off);
        dq6 += shflx(dq6, off); dq7 += shflx(dq7, off);
    }
    __syncthreads();

    {
        float dqj = sel8f(dq0, dq1, dq2, dq3, dq4, dq5, dq6, dq7, j);
        float sim = dqj / (sqrtf(dd) * qn_s[j] + 1e-8f);
        float u = (sim - 0.001f) / 0.999f * 30.0f;
        int bin = (int)floorf(u);
        bin = bin < 0 ? 0 : (bin > 29 ? 29 : bin);
        atomicAdd(&histw[wid][j][bin], 1.0f);
    }
    __syncthreads();

    if (tid < 240) {
        int q = tid / 30, k = tid - q * 30;
        float s = ((histw[0][q][k] + histw[1][q][k])
                 + (histw[2][q][k] + histw[3][q][k]))
                + ((histw[4][q][k] + histw[5][q][k])
                 + (histw[6][q][k] + histw[7][q][k]));
        atomicAdd(&hist_out[(bid >> 3) * 240 + tid], s);
    }
}

// ---------------- K5: gate softmax + MLP + output ----------------
// MODE 0: hist_g = [512][240] final. MODE 3: 16-slot partials [16][512][240].
template <int MODE>
__global__ __launch_bounds__(512, 3)
void drmm_mlp(const float* __restrict__ hist_g,
              const int* __restrict__ query,
              const float* __restrict__ idf,
              const float* __restrict__ w_gate,
              const float* __restrict__ g_in, const float* __restrict__ b_in,
              const float* __restrict__ W0, const float* __restrict__ b0,
              const float* __restrict__ g0, const float* __restrict__ be0,
              const float* __restrict__ W1, const float* __restrict__ b1,
              const float* __restrict__ g1, const float* __restrict__ be1,
              const float* __restrict__ W2, const float* __restrict__ b2,
              const float* __restrict__ g2, const float* __restrict__ be2,
              const float* __restrict__ W3, const float* __restrict__ b3,
              const float* __restrict__ g3, const float* __restrict__ be3,
              float* __restrict__ out)
{
    __shared__ float W1l[8192];
    __shared__ float xrow[8][30];
    __shared__ float h1s[8][128];
    __shared__ float h2s[8][64];
    __shared__ float h3s[8][32];
    __shared__ float gate_s[8];
    __shared__ float part[8];

    const int tid  = threadIdx.x;
    const int bd   = blockIdx.x;
    const int b    = bd >> 4;
    const int wid  = tid >> 6;
    const int lane = tid & 63;

#pragma unroll
    for (int i = 0; i < 4; ++i)
        ((float4*)W1l)[tid + i * 512] = ((const float4*)W1)[tid + i * 512];

    if (tid >= 504) {
        int q = tid - 504;
        float z = w_gate[q] * idf[query[b * 8 + q]];
        float m = z;
        m = fmaxf(m, shflx(m, 1)); m = fmaxf(m, shflx(m, 2)); m = fmaxf(m, shflx(m, 4));
        float e = expf(z - m);
        float s = e;
        s += shflx(s, 1); s += shflx(s, 2); s += shflx(s, 4);
        gate_s[q] = e / s;
    }

    if (tid < 240) {
        int q = tid / 30, k = tid - q * 30;
        float s;
        if (MODE == 3) {
            const float* hp = hist_g + (size_t)bd * 240 + tid;
            s = 0.f;
#pragma unroll
            for (int slot = 0; slot < 16; ++slot)
                s += hp[(size_t)slot * 512 * 240];   // exact int counts
        } else {
            s = hist_g[bd * 240 + tid];
        }
        xrow[q][k] = g_in[k] * (s * BN_INV) + b_in[k];
    }
    __syncthreads();

    {
        float a0 = 0.f, a1 = 0.f;
#pragma unroll
        for (int k = 0; k < 30; ++k) {
            float xk = xrow[wid][k];
            a0 += xk * W0[k * 128 + lane];
            a1 += xk * W0[k * 128 + 64 + lane];
        }
        a0 += b0[lane]; a1 += b0[lane + 64];
        h1s[wid][lane]      = tanh_fast(g0[lane]      * (a0 * BN_INV) + be0[lane]);
        h1s[wid][lane + 64] = tanh_fast(g0[lane + 64] * (a1 * BN_INV) + be0[lane + 64]);
    }
    __syncthreads();

    {
        float a = 0.f;
#pragma unroll 16
        for (int k = 0; k < 128; ++k) a += h1s[wid][k] * W1l[k * 64 + lane];
        a += b1[lane];
        h2s[wid][lane] = tanh_fast(g1[lane] * (a * BN_INV) + be1[lane]);
    }
    __syncthreads();

    if (lane < 32) {
        float a = 0.f;
#pragma unroll 8
        for (int k = 0; k < 64; ++k) a += h2s[wid][k] * W2[k * 32 + lane];
        a += b2[lane];
        h3s[wid][lane] = tanh_fast(g2[lane] * (a * BN_INV) + be2[lane]);
    }

    if (lane == 0) {
        float a = 0.f;
#pragma unroll
        for (int k = 0; k < 32; ++k) a += h3s[wid][k] * W3[k];
        a += b3[0];
        float y = tanh_fast(g3[0] * (a * BN_INV) + be3[0]);
        part[wid] = gate_s[wid] * y;
    }
    __syncthreads();

    if (tid == 0) {
        float s = 0.f;
#pragma unroll
        for (int q = 0; q < 8; ++q) s += part[q];
        out[bd] = s;
    }
}

extern "C" void kernel_launch(void* const* d_in, const int* in_sizes, int n_in,
                              void* d_out, int out_size, void* d_ws, size_t ws_size,
                              hipStream_t stream) {
    (void)in_sizes; (void)n_in; (void)out_size;
    const int*   doc    = (const int*)d_in[0];
    const int*   query  = (const int*)d_in[1];
    const float* emb    = (const float*)d_in[2];
    const float* idf    = (const float*)d_in[3];
    const float* w_gate = (const float*)d_in[4];
    const float* g_in   = (const float*)d_in[5];
    const float* b_in   = (const float*)d_in[6];
    const float* W0  = (const float*)d_in[7];
    const float* b0  = (const float*)d_in[8];
    const float* g0  = (const float*)d_in[9];
    const float* be0 = (const float*)d_in[10];
    const float* W1  = (const float*)d_in[11];
    const float* b1  = (const float*)d_in[12];
    const float* g1  = (const float*)d_in[13];
    const float* be1 = (const float*)d_in[14];
    const float* W2  = (const float*)d_in[15];
    const float* b2  = (const float*)d_in[16];
    const float* g2  = (const float*)d_in[17];
    const float* be2 = (const float*)d_in[18];
    const float* W3  = (const float*)d_in[19];
    const float* b3  = (const float*)d_in[20];
    const float* g3  = (const float*)d_in[21];
    const float* be3 = (const float*)d_in[22];

    const size_t HIST_PART_B = (size_t)16 * 512 * 240 * sizeof(float); // 7.86 MB
    const size_t need_sorted = HIST_PART_B
                             + 2 * 8192 * sizeof(unsigned)             // counts+offsets
                             + (size_t)262144 * sizeof(unsigned);      // packed ~9.0 MB

    if (ws_size >= need_sorted) {
        float*    hist_part = (float*)d_ws;
        unsigned* counts  = (unsigned*)((char*)d_ws + HIST_PART_B);
        unsigned* offsets = counts + 8192;
        unsigned* packed  = offsets + 8192;

        k_count  <<<dim3(512), dim3(512), 0, stream>>>(doc, counts);
        k_scan   <<<dim3(1),   dim3(512), 0, stream>>>(counts, offsets);
        k_scatter<<<dim3(512), dim3(512), 0, stream>>>(doc, offsets, packed);
        k_hist_sorted<<<dim3(512), dim3(512), 0, stream>>>(
            packed, offsets, query, emb, hist_part);
        drmm_mlp<3><<<dim3(512), dim3(512), 0, stream>>>(
            hist_part, query, idf, w_gate, g_in, b_in,
            W0, b0, g0, be0, W1, b1, g1, be1,
            W2, b2, g2, be2, W3, b3, g3, be3, (float*)d_out);
    } else {
        float* hist_g = (float*)d_ws;
        hipMemsetAsync(hist_g, 0, 512 * 240 * sizeof(float), stream);
        drmm_hist_atomic<<<dim3(4096), dim3(512), 0, stream>>>(doc, query, emb, hist_g);
        drmm_mlp<0><<<dim3(512), dim3(512), 0, stream>>>(
            hist_g, query, idf, w_gate, g_in, b_in,
            W0, b0, g0, be0, W1, b1, g1, be1,
            W2, b2, g2, be2, W3, b3, g3, be3, (float*)d_out);
    }
}

// Round 15
// 47.110 us; speedup vs baseline: 5.2820x; 1.3410x over previous
//
#include <hip/hip_runtime.h>
#include <math.h>

// DRMM pipeline for MI355X (gfx950) — round 15: T=4 token amortization of
// q-reads. 8-lane group owns 4 tokens; each qlds read (a0..a7) feeds 4 rows
// held in registers (A/B ping-pong, 2 lines deep). q-LDS traffic 4x lower
// than R12; per-token FMA/butterfly/bin order bit-identical to R12.
// Phase 1: 1024 blocks x 512 thr. Phase 2: R11 MLP (W1 in LDS).
// B=32, D=16, L=512, Q=8, E=128, NB=30

#define BN_INV 0.99950037468777346f  // np.float32(1/sqrt(1+1e-3))

__device__ __forceinline__ float shflx(float v, int m) {
    return __shfl_xor(v, m, 64);
}

__device__ __forceinline__ int sel8i(int v0, int v1, int v2, int v3,
                                     int v4, int v5, int v6, int v7, int i) {
    int a0 = (i & 1) ? v1 : v0;
    int a1 = (i & 1) ? v3 : v2;
    int a2 = (i & 1) ? v5 : v4;
    int a3 = (i & 1) ? v7 : v6;
    int b0 = (i & 2) ? a1 : a0;
    int b1 = (i & 2) ? a3 : a2;
    return (i & 4) ? b1 : b0;
}

__device__ __forceinline__ float sel8f(float v0, float v1, float v2, float v3,
                                       float v4, float v5, float v6, float v7, int i) {
    float a0 = (i & 1) ? v1 : v0;
    float a1 = (i & 1) ? v3 : v2;
    float a2 = (i & 1) ? v5 : v4;
    float a3 = (i & 1) ? v7 : v6;
    float b0 = (i & 2) ? a1 : a0;
    float b1 = (i & 2) ? a3 : a2;
    return (i & 4) ? b1 : b0;
}

// fast tanh: clamp(+-9) then (e^2x-1)/(e^2x+1) via hw exp2 + rcp. (R6-R14: absmax 0.0)
__device__ __forceinline__ float tanh_fast(float x) {
    float y = fminf(fmaxf(x, -9.0f), 9.0f);
    float t = exp2f(y * 2.8853901817f);      // e^(2y)
    return (t - 1.0f) * __builtin_amdgcn_rcpf(t + 1.0f);
}

__device__ __forceinline__ float4 ld4(const float* base, int elem_off) {
    return *(const float4*)(base + elem_off);
}

#define PIN4(V) asm volatile("" : "+v"((V).x), "+v"((V).y), "+v"((V).z), "+v"((V).w))

// one token's FMA update for one 16-elem slice — order identical to R12 KSTEP.
#define FMA1(v, A, ACC) ACC = fmaf(v.x, (A).x, ACC); ACC = fmaf(v.y, (A).y, ACC); \
                        ACC = fmaf(v.z, (A).z, ACC); ACC = fmaf(v.w, (A).w, ACC);
#define TOKSTEP(V, T) { \
        float4 v = (V); \
        dd##T = fmaf(v.x, v.x, dd##T); dd##T = fmaf(v.y, v.y, dd##T); \
        dd##T = fmaf(v.z, v.z, dd##T); dd##T = fmaf(v.w, v.w, dd##T); \
        FMA1(v, a0, dq0_##T) FMA1(v, a1, dq1_##T) \
        FMA1(v, a2, dq2_##T) FMA1(v, a3, dq3_##T) \
        FMA1(v, a4, dq4_##T) FMA1(v, a5, dq5_##T) \
        FMA1(v, a6, dq6_##T) FMA1(v, a7, dq7_##T) \
    }
// one K-slice: read a0..a7 ONCE, apply to 4 tokens.
#define KBLOCK(R0, R1, R2, R3, K) { \
        const int S = (K) * 8 + j; \
        float4 a0 = qlds[0][S], a1 = qlds[1][S]; \
        float4 a2 = qlds[2][S], a3 = qlds[3][S]; \
        float4 a4 = qlds[4][S], a5 = qlds[5][S]; \
        float4 a6 = qlds[6][S], a7 = qlds[7][S]; \
        TOKSTEP(R0, 0) TOKSTEP(R1, 1) TOKSTEP(R2, 2) TOKSTEP(R3, 3) \
    }

// ---------------- Phase 1: gather + histogram (T=4 per group) ----------------
template <bool PARTIAL>
__global__ __launch_bounds__(512, 4)
void drmm_hist(const int* __restrict__ doc,
               const int* __restrict__ query,
               const float* __restrict__ emb,
               float* __restrict__ hist_out)
{
    __shared__ float histw[8][8][32];   // [wave][q][bin(+2 pad)] 8KB
    __shared__ float qn_s[8];
    __shared__ float4 qlds[8][32];      // 4KB

    const int tid  = threadIdx.x;
    const int bid  = blockIdx.x;        // 0..1023, 256 tokens each (one bd half)
    const int b    = bid >> 5;          // batch
    const int wid  = tid >> 6;
    const int lane = tid & 63;
    const int g    = lane >> 3;         // group in wave 0..7
    const int j    = lane & 7;          // lane in group

    // 4 doc indices per group (one int4; group lanes share the address)
    const int tokbase = bid * 256 + wid * 32 + g * 4;
    const int4 idxv = *(const int4*)(doc + tokbase);

    for (int i = tid; i < 8 * 8 * 32; i += 512) ((float*)histw)[i] = 0.0f;

    const int* qrow = query + b * 8;
    const int qi0 = __builtin_amdgcn_readfirstlane(qrow[0]);
    const int qi1 = __builtin_amdgcn_readfirstlane(qrow[1]);
    const int qi2 = __builtin_amdgcn_readfirstlane(qrow[2]);
    const int qi3 = __builtin_amdgcn_readfirstlane(qrow[3]);
    const int qi4 = __builtin_amdgcn_readfirstlane(qrow[4]);
    const int qi5 = __builtin_amdgcn_readfirstlane(qrow[5]);
    const int qi6 = __builtin_amdgcn_readfirstlane(qrow[6]);
    const int qi7 = __builtin_amdgcn_readfirstlane(qrow[7]);

    if (tid < 256) {
        int q = tid >> 5, c = tid & 31;
        int qis = sel8i(qi0, qi1, qi2, qi3, qi4, qi5, qi6, qi7, q);
        qlds[q][c] = *((const float4*)(emb + (size_t)qis * 128) + c);
    }
    __syncthreads();

    // query norms: wave 0, from LDS (values & op order identical to R11/R12)
    if (wid == 0) {
        int q = lane >> 3, jj = lane & 7;
        float s = 0.f;
#pragma unroll
        for (int c = 0; c < 4; ++c) {
            float4 x = qlds[q][jj * 4 + c];
            s = fmaf(x.x, x.x, s); s = fmaf(x.y, x.y, s);
            s = fmaf(x.z, x.z, s); s = fmaf(x.w, x.w, s);
        }
        s += shflx(s, 1); s += shflx(s, 2); s += shflx(s, 4);
        if (jj == 0) qn_s[q] = sqrtf(s);
    }

    // ---- 4 rows, A/B ping-pong 2 lines deep ----
    const int eo = j * 4;
    const float* rb0 = emb + (size_t)idxv.x * 128;
    const float* rb1 = emb + (size_t)idxv.y * 128;
    const float* rb2 = emb + (size_t)idxv.z * 128;
    const float* rb3 = emb + (size_t)idxv.w * 128;

    float4 RA0 = ld4(rb0, eo),      RA1 = ld4(rb1, eo);
    float4 RA2 = ld4(rb2, eo),      RA3 = ld4(rb3, eo);
    float4 RB0 = ld4(rb0, eo + 32), RB1 = ld4(rb1, eo + 32);
    float4 RB2 = ld4(rb2, eo + 32), RB3 = ld4(rb3, eo + 32);

    float dd0 = 0.f, dd1 = 0.f, dd2 = 0.f, dd3 = 0.f;
    float dq0_0=0.f, dq1_0=0.f, dq2_0=0.f, dq3_0=0.f, dq4_0=0.f, dq5_0=0.f, dq6_0=0.f, dq7_0=0.f;
    float dq0_1=0.f, dq1_1=0.f, dq2_1=0.f, dq3_1=0.f, dq4_1=0.f, dq5_1=0.f, dq6_1=0.f, dq7_1=0.f;
    float dq0_2=0.f, dq1_2=0.f, dq2_2=0.f, dq3_2=0.f, dq4_2=0.f, dq5_2=0.f, dq6_2=0.f, dq7_2=0.f;
    float dq0_3=0.f, dq1_3=0.f, dq2_3=0.f, dq3_3=0.f, dq4_3=0.f, dq5_3=0.f, dq6_3=0.f, dq7_3=0.f;

    PIN4(RA0); PIN4(RA1); PIN4(RA2); PIN4(RA3);
    KBLOCK(RA0, RA1, RA2, RA3, 0)
    RA0 = ld4(rb0, eo + 64); RA1 = ld4(rb1, eo + 64);
    RA2 = ld4(rb2, eo + 64); RA3 = ld4(rb3, eo + 64);
    PIN4(RB0); PIN4(RB1); PIN4(RB2); PIN4(RB3);
    KBLOCK(RB0, RB1, RB2, RB3, 1)
    RB0 = ld4(rb0, eo + 96); RB1 = ld4(rb1, eo + 96);
    RB2 = ld4(rb2, eo + 96); RB3 = ld4(rb3, eo + 96);
    PIN4(RA0); PIN4(RA1); PIN4(RA2); PIN4(RA3);
    KBLOCK(RA0, RA1, RA2, RA3, 2)
    PIN4(RB0); PIN4(RB1); PIN4(RB2); PIN4(RB3);
    KBLOCK(RB0, RB1, RB2, RB3, 3)

    // butterfly within each 8-lane group — per-token order identical to R12
#pragma unroll
    for (int off = 1; off <= 4; off <<= 1) {
        dd0 += shflx(dd0, off); dd1 += shflx(dd1, off);
        dd2 += shflx(dd2, off); dd3 += shflx(dd3, off);
        dq0_0 += shflx(dq0_0, off); dq1_0 += shflx(dq1_0, off);
        dq2_0 += shflx(dq2_0, off); dq3_0 += shflx(dq3_0, off);
        dq4_0 += shflx(dq4_0, off); dq5_0 += shflx(dq5_0, off);
        dq6_0 += shflx(dq6_0, off); dq7_0 += shflx(dq7_0, off);
        dq0_1 += shflx(dq0_1, off); dq1_1 += shflx(dq1_1, off);
        dq2_1 += shflx(dq2_1, off); dq3_1 += shflx(dq3_1, off);
        dq4_1 += shflx(dq4_1, off); dq5_1 += shflx(dq5_1, off);
        dq6_1 += shflx(dq6_1, off); dq7_1 += shflx(dq7_1, off);
        dq0_2 += shflx(dq0_2, off); dq1_2 += shflx(dq1_2, off);
        dq2_2 += shflx(dq2_2, off); dq3_2 += shflx(dq3_2, off);
        dq4_2 += shflx(dq4_2, off); dq5_2 += shflx(dq5_2, off);
        dq6_2 += shflx(dq6_2, off); dq7_2 += shflx(dq7_2, off);
        dq0_3 += shflx(dq0_3, off); dq1_3 += shflx(dq1_3, off);
        dq2_3 += shflx(dq2_3, off); dq3_3 += shflx(dq3_3, off);
        dq4_3 += shflx(dq4_3, off); dq5_3 += shflx(dq5_3, off);
        dq6_3 += shflx(dq6_3, off); dq7_3 += shflx(dq7_3, off);
    }

    __syncthreads();             // qn_s ready for all waves

#define DOBIN(T) { \
        float dqj = sel8f(dq0_##T, dq1_##T, dq2_##T, dq3_##T, \
                          dq4_##T, dq5_##T, dq6_##T, dq7_##T, j); \
        float sim = dqj / (sqrtf(dd##T) * qn_s[j] + 1e-8f); \
        float u = (sim - 0.001f) / 0.999f * 30.0f; \
        int bin = (int)floorf(u); \
        bin = bin < 0 ? 0 : (bin > 29 ? 29 : bin); \
        atomicAdd(&histw[wid][j][bin], 1.0f); \
    }
    DOBIN(0) DOBIN(1) DOBIN(2) DOBIN(3)
#undef DOBIN
    __syncthreads();

    // flush 8q x 30 bins (exact integer counts)
    if (tid < 240) {
        int q = tid / 30, k = tid - q * 30;
        float s = ((histw[0][q][k] + histw[1][q][k])
                 + (histw[2][q][k] + histw[3][q][k]))
                + ((histw[4][q][k] + histw[5][q][k])
                 + (histw[6][q][k] + histw[7][q][k]));
        if (PARTIAL) {
            hist_out[(size_t)bid * 240 + tid] = s;
        } else {
            atomicAdd(&hist_out[(bid >> 1) * 240 + tid], s);
        }
    }
}

// ---------------- Phase 2: gate softmax + MLP + output ----------------
template <bool PARTIAL>
__global__ __launch_bounds__(512, 3)
void drmm_mlp(const float* __restrict__ hist_g,
              const int* __restrict__ query,
              const float* __restrict__ idf,
              const float* __restrict__ w_gate,
              const float* __restrict__ g_in, const float* __restrict__ b_in,
              const float* __restrict__ W0, const float* __restrict__ b0,
              const float* __restrict__ g0, const float* __restrict__ be0,
              const float* __restrict__ W1, const float* __restrict__ b1,
              const float* __restrict__ g1, const float* __restrict__ be1,
              const float* __restrict__ W2, const float* __restrict__ b2,
              const float* __restrict__ g2, const float* __restrict__ be2,
              const float* __restrict__ W3, const float* __restrict__ b3,
              const float* __restrict__ g3, const float* __restrict__ be3,
              float* __restrict__ out)
{
    __shared__ float W1l[8192];
    __shared__ float xrow[8][30];
    __shared__ float h1s[8][128];
    __shared__ float h2s[8][64];
    __shared__ float h3s[8][32];
    __shared__ float gate_s[8];
    __shared__ float part[8];

    const int tid  = threadIdx.x;
    const int bd   = blockIdx.x;
    const int b    = bd >> 4;
    const int wid  = tid >> 6;
    const int lane = tid & 63;

#pragma unroll
    for (int i = 0; i < 4; ++i)
        ((float4*)W1l)[tid + i * 512] = ((const float4*)W1)[tid + i * 512];

    if (tid >= 504) {
        int q = tid - 504;
        float z = w_gate[q] * idf[query[b * 8 + q]];
        float m = z;
        m = fmaxf(m, shflx(m, 1)); m = fmaxf(m, shflx(m, 2)); m = fmaxf(m, shflx(m, 4));
        float e = expf(z - m);
        float s = e;
        s += shflx(s, 1); s += shflx(s, 2); s += shflx(s, 4);
        gate_s[q] = e / s;
    }

    if (tid < 240) {
        int q = tid / 30, k = tid - q * 30;
        float s;
        if (PARTIAL) {
            const float* hp = hist_g + (size_t)bd * 480 + tid;
            s = hp[0] + hp[240];  // exact int counts
        } else {
            s = hist_g[bd * 240 + tid];
        }
        xrow[q][k] = g_in[k] * (s * BN_INV) + b_in[k];
    }
    __syncthreads();

    {
        float a0 = 0.f, a1 = 0.f;
#pragma unroll
        for (int k = 0; k < 30; ++k) {
            float xk = xrow[wid][k];
            a0 += xk * W0[k * 128 + lane];
            a1 += xk * W0[k * 128 + 64 + lane];
        }
        a0 += b0[lane]; a1 += b0[lane + 64];
        h1s[wid][lane]      = tanh_fast(g0[lane]      * (a0 * BN_INV) + be0[lane]);
        h1s[wid][lane + 64] = tanh_fast(g0[lane + 64] * (a1 * BN_INV) + be0[lane + 64]);
    }
    __syncthreads();

    {
        float a = 0.f;
#pragma unroll 16
        for (int k = 0; k < 128; ++k) a += h1s[wid][k] * W1l[k * 64 + lane];
        a += b1[lane];
        h2s[wid][lane] = tanh_fast(g1[lane] * (a * BN_INV) + be1[lane]);
    }
    __syncthreads();

    if (lane < 32) {
        float a = 0.f;
#pragma unroll 8
        for (int k = 0; k < 64; ++k) a += h2s[wid][k] * W2[k * 32 + lane];
        a += b2[lane];
        h3s[wid][lane] = tanh_fast(g2[lane] * (a * BN_INV) + be2[lane]);
    }

    if (lane == 0) {
        float a = 0.f;
#pragma unroll
        for (int k = 0; k < 32; ++k) a += h3s[wid][k] * W3[k];
        a += b3[0];
        float y = tanh_fast(g3[0] * (a * BN_INV) + be3[0]);
        part[wid] = gate_s[wid] * y;
    }
    __syncthreads();

    if (tid == 0) {
        float s = 0.f;
#pragma unroll
        for (int q = 0; q < 8; ++q) s += part[q];
        out[bd] = s;
    }
}

extern "C" void kernel_launch(void* const* d_in, const int* in_sizes, int n_in,
                              void* d_out, int out_size, void* d_ws, size_t ws_size,
                              hipStream_t stream) {
    (void)in_sizes; (void)n_in; (void)out_size;
    const int*   doc    = (const int*)d_in[0];
    const int*   query  = (const int*)d_in[1];
    const float* emb    = (const float*)d_in[2];
    const float* idf    = (const float*)d_in[3];
    const float* w_gate = (const float*)d_in[4];
    const float* g_in   = (const float*)d_in[5];
    const float* b_in   = (const float*)d_in[6];
    const float* W0  = (const float*)d_in[7];
    const float* b0  = (const float*)d_in[8];
    const float* g0  = (const float*)d_in[9];
    const float* be0 = (const float*)d_in[10];
    const float* W1  = (const float*)d_in[11];
    const float* b1  = (const float*)d_in[12];
    const float* g1  = (const float*)d_in[13];
    const float* be1 = (const float*)d_in[14];
    const float* W2  = (const float*)d_in[15];
    const float* b2  = (const float*)d_in[16];
    const float* g2  = (const float*)d_in[17];
    const float* be2 = (const float*)d_in[18];
    const float* W3  = (const float*)d_in[19];
    const float* b3  = (const float*)d_in[20];
    const float* g3  = (const float*)d_in[21];
    const float* be3 = (const float*)d_in[22];

    float* hist_g = (float*)d_ws;
    const size_t need_partial = (size_t)1024 * 240 * sizeof(float); // 983 KB

    if (ws_size >= need_partial) {
        drmm_hist<true><<<dim3(1024), dim3(512), 0, stream>>>(doc, query, emb, hist_g);
        drmm_mlp<true><<<dim3(512), dim3(512), 0, stream>>>(
            hist_g, query, idf, w_gate, g_in, b_in,
            W0, b0, g0, be0, W1, b1, g1, be1,
            W2, b2, g2, be2, W3, b3, g3, be3, (float*)d_out);
    } else {
        hipMemsetAsync(hist_g, 0, 512 * 240 * sizeof(float), stream);
        drmm_hist<false><<<dim3(1024), dim3(512), 0, stream>>>(doc, query, emb, hist_g);
        drmm_mlp<false><<<dim3(512), dim3(512), 0, stream>>>(
            hist_g, query, idf, w_gate, g_in, b_in,
            W0, b0, g0, be0, W1, b1, g1, be1,
            W2, b2, g2, be2, W3, b3, g3, be3, (float*)d_out);
    }
}